// Round 4
// baseline (24449.162 us; speedup 1.0000x reference)
//
#include <hip/hip_runtime.h>

typedef _Float16 f16;
typedef _Float16 f16x8 __attribute__((ext_vector_type(8)));
typedef float f32x16 __attribute__((ext_vector_type(16)));

#define HID   512
#define BT    64
#define NSTEP 100
#define WMAT  786432   // halfs per packed weight matrix (1536*512)

__device__ __forceinline__ float sigmoid_f(float x) {
  return 1.0f / (1.0f + __expf(-x));
}
__device__ __forceinline__ float tanh_f(float x) {
  float e = __expf(2.0f * x);
  return 1.0f - 2.0f / (e + 1.0f);
}
__device__ __forceinline__ f32x16 mfma16(f16x8 a, f16x8 b, f32x16 c) {
  return __builtin_amdgcn_mfma_f32_32x32x16_f16(a, b, c, 0, 0, 0);
}
__device__ __forceinline__ f32x16 zero16() {
  f32x16 z;
#pragma unroll
  for (int i = 0; i < 16; ++i) z[i] = 0.f;
  return z;
}

// ---- weight pack: fp32 [1536][512] row-major -> B-fragment-packed fp16 ----
// layout [ct(48)][kt(32)][lane(64)][i(8)]:
//   gate = ct*32 + (lane&31), k = kt*16 + (lane>>5)*8 + i
__global__ void pack_weights(const float* __restrict__ W, f16* __restrict__ out) {
  int t = blockIdx.x * 256 + threadIdx.x;
  if (t >= 48 * 32 * 64) return;
  int lane = t & 63;
  int kt   = (t >> 6) & 31;
  int ct   = t >> 11;
  int gate = ct * 32 + (lane & 31);
  int k0   = kt * 16 + (lane >> 5) * 8;
  const float* src = W + gate * HID + k0;
  f16x8 v;
#pragma unroll
  for (int i = 0; i < 8; ++i) v[i] = (f16)src[i];
  *(f16x8*)(out + (size_t)t * 8) = v;
}

// w_ih1 [1536][3] -> B-fragments padded to K=16 (zeros for k>=3); 48 tiles x 512 halfs
__global__ void pack_wih1(const float* __restrict__ W, f16* __restrict__ out) {
  int t = blockIdx.x * 256 + threadIdx.x;
  if (t >= 48 * 64) return;
  int lane = t & 63;
  int ct   = t >> 6;
  int gate = ct * 32 + (lane & 31);
  int k0   = (lane >> 5) * 8;
  f16x8 v;
#pragma unroll
  for (int i = 0; i < 8; ++i) {
    int k = k0 + i;
    v[i] = (k < 3) ? (f16)W[gate * 3 + k] : (f16)0;
  }
  *(f16x8*)(out + (size_t)t * 8) = v;
}

// combined biases: [0..1023]=bi+bh (r,z), [1024..1535]=bi_n, [1536..2047]=bh_n
__global__ void pack_bias(const float* __restrict__ bi, const float* __restrict__ bh,
                          float* __restrict__ out) {
  int j = blockIdx.x * 256 + threadIdx.x;
  if (j < 1024)      out[j] = bi[j] + bh[j];
  else if (j < 1536) out[j] = bi[j];
  else if (j < 2048) out[j] = bh[j - 512];
}

// Persistent per-block GRU: block = 64 batch rows, 8 waves, 99 steps.
// h element (row,k) at LDS byte: row*1024 + ((2k) ^ ((row&7)<<4))
__global__ __launch_bounds__(512, 2) void gru_fused(
    const float* __restrict__ z,
    const float* __restrict__ fc_w,    // [3][512]  fp32
    const float* __restrict__ fc_b,    // [3]
    const f16*  __restrict__ Wp,       // packed Whh1 | Wih2 | Whh2
    const f16*  __restrict__ Wx,       // packed w_ih1 (K=16 padded)
    const float* __restrict__ Bb,      // bias1[2048] | bias2[2048]
    float* __restrict__ out)           // [B][100][3] fp32
{
  __shared__ f16   h1s[BT * HID];       // 64 KB
  __shared__ f16   h2s[BT * HID];       // 64 KB
  __shared__ f16   xs16[BT * 16];       // 2 KB  (x as MFMA A-tile, K=16 zero-padded)
  __shared__ float fcw[HID * 4];        // 8 KB  (fc_w transposed [k][oo])
  __shared__ float part[8 * BT * 4];    // 8 KB  (FC partial sums)

  const int tid  = threadIdx.x;
  const int lane = tid & 63;
  const int wv   = tid >> 6;
  const int b0   = blockIdx.x * BT;

  {
    f16x8 z8 = {0, 0, 0, 0, 0, 0, 0, 0};
    for (int i = tid; i < BT * HID / 8; i += 512) {
      ((f16x8*)h1s)[i] = z8;
      ((f16x8*)h2s)[i] = z8;
    }
    if (tid < BT * 2) ((f16x8*)xs16)[tid] = z8;
    if (tid < HID) {
      fcw[tid * 4 + 0] = fc_w[tid];
      fcw[tid * 4 + 1] = fc_w[HID + tid];
      fcw[tid * 4 + 2] = fc_w[2 * HID + tid];
      fcw[tid * 4 + 3] = 0.f;
    }
  }
  __syncthreads();

  int rr_ = 0, oo_ = 0;
  float xcar = 0.f, fb = 0.f;
  if (tid < BT * 3) {
    rr_ = tid / 3;
    oo_ = tid - rr_ * 3;
    xcar = z[(size_t)(b0 + rr_) * 6 + 3 + oo_];
    fb   = fc_b[oo_];
    out[(size_t)(b0 + rr_) * 300 + oo_] = xcar;     // t = 0 output
    xs16[rr_ * 16 + oo_] = (f16)xcar;
  }
  __syncthreads();

  const int colid = lane & 31;
  const int khalf = lane >> 5;
  const int klo   = khalf << 4;
  const int patA  = (colid & 7) << 4;
  const int rbase0 = colid * 1024;
  const int rbase1 = (32 + colid) * 1024;
  const int jw = wv << 6;

  const f16* W1  = Wp;
  const f16* Wi2 = Wp + WMAT;
  const f16* Wh2 = Wp + 2 * WMAT;

  // bias registers (constant over t) as named scalars
  const int j0 = jw + colid, j1 = jw + 32 + colid;
  const float b1r0 = Bb[j0],        b1r1 = Bb[j1];
  const float b1z0 = Bb[512 + j0],  b1z1 = Bb[512 + j1];
  const float b1ni0 = Bb[1024 + j0], b1ni1 = Bb[1024 + j1];
  const float b1nh0 = Bb[1536 + j0], b1nh1 = Bb[1536 + j1];
  const float b2r0 = Bb[2048 + j0],        b2r1 = Bb[2048 + j1];
  const float b2z0 = Bb[2048 + 512 + j0],  b2z1 = Bb[2048 + 512 + j1];
  const float b2ni0 = Bb[2048 + 1024 + j0], b2ni1 = Bb[2048 + 1024 + j1];
  const float b2nh0 = Bb[2048 + 1536 + j0], b2nh1 = Bb[2048 + 1536 + j1];

  const int xoff0 = colid * 32 + klo;        // xs16 byte offset, rows 0..31
  const int xoff1 = (32 + colid) * 32 + klo; // rows 32..63

  for (int t = 1; t < NSTEP; ++t) {
    f16x8 hv[8];   // new-h for one layer, [c(2)][rt(2)][qhi(2)] x 8 lanes

    // ================= GRU layer 1 (two passes per 32-col chunk) =================
#pragma unroll
    for (int c = 0; c < 2; ++c) {
      const int jb = jw + (c << 5);
      const float brc  = c ? b1r1 : b1r0;
      const float bzc  = c ? b1z1 : b1z0;
      const float bnic = c ? b1ni1 : b1ni0;
      const float bnhc = c ? b1nh1 : b1nh0;
      f16x8 rv[4], zv[4];

      // ---- pass 1: r,z gates ----
      {
        f32x16 aR[2], aZ[2];
        {
          f16x8 ax0 = *(const f16x8*)((const char*)xs16 + xoff0);
          f16x8 ax1 = *(const f16x8*)((const char*)xs16 + xoff1);
          f16x8 brx = *(const f16x8*)(Wx + (size_t)((jb) >> 5) * 512 + lane * 8);
          f16x8 bzx = *(const f16x8*)(Wx + (size_t)((512 + jb) >> 5) * 512 + lane * 8);
          f32x16 zz = zero16();
          aR[0] = mfma16(ax0, brx, zz);  aR[1] = mfma16(ax1, brx, zz);
          aZ[0] = mfma16(ax0, bzx, zz);  aZ[1] = mfma16(ax1, bzx, zz);
        }
        const f16* Br = W1 + (size_t)((jb) >> 5) * 16384 + lane * 8;
        const f16* Bz = W1 + (size_t)((512 + jb) >> 5) * 16384 + lane * 8;
#pragma unroll 2
        for (int kt = 0; kt < 32; ++kt) {
          const int koff = ((kt << 5) | klo) ^ patA;
          f16x8 a0 = *(const f16x8*)((const char*)h1s + rbase0 + koff);
          f16x8 a1 = *(const f16x8*)((const char*)h1s + rbase1 + koff);
          f16x8 br = *(const f16x8*)(Br + kt * 512);
          f16x8 bz = *(const f16x8*)(Bz + kt * 512);
          aR[0] = mfma16(a0, br, aR[0]);  aR[1] = mfma16(a1, br, aR[1]);
          aZ[0] = mfma16(a0, bz, aZ[0]);  aZ[1] = mfma16(a1, bz, aZ[1]);
        }
#pragma unroll
        for (int rt = 0; rt < 2; ++rt)
#pragma unroll
          for (int q = 0; q < 16; ++q) {
            rv[(rt << 1) | (q >> 3)][q & 7] = (f16)sigmoid_f(aR[rt][q] + brc);
            zv[(rt << 1) | (q >> 3)][q & 7] = (f16)sigmoid_f(aZ[rt][q] + bzc);
          }
      }

      // ---- pass 2: n gate + h update ----
      {
        f32x16 aN[2], aNx[2];
        {
          f16x8 ax0 = *(const f16x8*)((const char*)xs16 + xoff0);
          f16x8 ax1 = *(const f16x8*)((const char*)xs16 + xoff1);
          f16x8 bnx = *(const f16x8*)(Wx + (size_t)((1024 + jb) >> 5) * 512 + lane * 8);
          f32x16 zz = zero16();
          aNx[0] = mfma16(ax0, bnx, zz); aNx[1] = mfma16(ax1, bnx, zz);
          aN[0] = zz; aN[1] = zz;
        }
        const f16* Bn = W1 + (size_t)((1024 + jb) >> 5) * 16384 + lane * 8;
#pragma unroll 2
        for (int kt = 0; kt < 32; ++kt) {
          const int koff = ((kt << 5) | klo) ^ patA;
          f16x8 a0 = *(const f16x8*)((const char*)h1s + rbase0 + koff);
          f16x8 a1 = *(const f16x8*)((const char*)h1s + rbase1 + koff);
          f16x8 bn = *(const f16x8*)(Bn + kt * 512);
          aN[0] = mfma16(a0, bn, aN[0]);  aN[1] = mfma16(a1, bn, aN[1]);
        }
        const int jx = 2 * (jb + colid);
#pragma unroll
        for (int rt = 0; rt < 2; ++rt)
#pragma unroll
          for (int q = 0; q < 16; ++q) {
            const int row = (rt << 5) + (q & 3) + ((q >> 2) << 3) + (khalf << 2);
            float r  = (float)rv[(rt << 1) | (q >> 3)][q & 7];
            float zt = (float)zv[(rt << 1) | (q >> 3)][q & 7];
            float n  = tanh_f(aNx[rt][q] + bnic + r * (aN[rt][q] + bnhc));
            float hold = (float)*(const f16*)((const char*)h1s + row * 1024 + (jx ^ ((row & 7) << 4)));
            hv[(c << 2) | (rt << 1) | (q >> 3)][q & 7] = (f16)((1.0f - zt) * n + zt * hold);
          }
      }
    }
    __syncthreads();
#pragma unroll
    for (int c = 0; c < 2; ++c) {
      const int j2 = 2 * (jw + (c << 5) + colid);
#pragma unroll
      for (int rt = 0; rt < 2; ++rt)
#pragma unroll
        for (int q = 0; q < 16; ++q) {
          const int row = (rt << 5) + (q & 3) + ((q >> 2) << 3) + (khalf << 2);
          *(f16*)((char*)h1s + row * 1024 + (j2 ^ ((row & 7) << 4))) = hv[(c << 2) | (rt << 1) | (q >> 3)][q & 7];
        }
    }
    __syncthreads();

    // ================= GRU layer 2 (two passes per chunk) =================
#pragma unroll
    for (int c = 0; c < 2; ++c) {
      const int jb = jw + (c << 5);
      const float brc  = c ? b2r1 : b2r0;
      const float bzc  = c ? b2z1 : b2z0;
      const float bnic = c ? b2ni1 : b2ni0;
      const float bnhc = c ? b2nh1 : b2nh0;
      f16x8 rv[4], zv[4];

      // ---- pass 1: r,z gates (4 streams) ----
      {
        f32x16 aR[2], aZ[2];
        {
          f32x16 zz = zero16();
          aR[0] = zz; aR[1] = zz; aZ[0] = zz; aZ[1] = zz;
        }
        const f16* Bir = Wi2 + (size_t)((jb) >> 5) * 16384 + lane * 8;
        const f16* Biz = Wi2 + (size_t)((512 + jb) >> 5) * 16384 + lane * 8;
        const f16* Bhr = Wh2 + (size_t)((jb) >> 5) * 16384 + lane * 8;
        const f16* Bhz = Wh2 + (size_t)((512 + jb) >> 5) * 16384 + lane * 8;
#pragma unroll 2
        for (int kt = 0; kt < 32; ++kt) {
          const int koff = ((kt << 5) | klo) ^ patA;
          f16x8 a10 = *(const f16x8*)((const char*)h1s + rbase0 + koff);
          f16x8 a11 = *(const f16x8*)((const char*)h1s + rbase1 + koff);
          f16x8 a20 = *(const f16x8*)((const char*)h2s + rbase0 + koff);
          f16x8 a21 = *(const f16x8*)((const char*)h2s + rbase1 + koff);
          f16x8 bir = *(const f16x8*)(Bir + kt * 512);
          f16x8 biz = *(const f16x8*)(Biz + kt * 512);
          f16x8 bhr = *(const f16x8*)(Bhr + kt * 512);
          f16x8 bhz = *(const f16x8*)(Bhz + kt * 512);
          aR[0] = mfma16(a10, bir, aR[0]);  aR[0] = mfma16(a20, bhr, aR[0]);
          aR[1] = mfma16(a11, bir, aR[1]);  aR[1] = mfma16(a21, bhr, aR[1]);
          aZ[0] = mfma16(a10, biz, aZ[0]);  aZ[0] = mfma16(a20, bhz, aZ[0]);
          aZ[1] = mfma16(a11, biz, aZ[1]);  aZ[1] = mfma16(a21, bhz, aZ[1]);
        }
#pragma unroll
        for (int rt = 0; rt < 2; ++rt)
#pragma unroll
          for (int q = 0; q < 16; ++q) {
            rv[(rt << 1) | (q >> 3)][q & 7] = (f16)sigmoid_f(aR[rt][q] + brc);
            zv[(rt << 1) | (q >> 3)][q & 7] = (f16)sigmoid_f(aZ[rt][q] + bzc);
          }
      }

      // ---- pass 2: n gate + h update (2 streams) ----
      {
        f32x16 aI[2], aH[2];
        {
          f32x16 zz = zero16();
          aI[0] = zz; aI[1] = zz; aH[0] = zz; aH[1] = zz;
        }
        const f16* Bin = Wi2 + (size_t)((1024 + jb) >> 5) * 16384 + lane * 8;
        const f16* Bhn = Wh2 + (size_t)((1024 + jb) >> 5) * 16384 + lane * 8;
#pragma unroll 2
        for (int kt = 0; kt < 32; ++kt) {
          const int koff = ((kt << 5) | klo) ^ patA;
          f16x8 a10 = *(const f16x8*)((const char*)h1s + rbase0 + koff);
          f16x8 a11 = *(const f16x8*)((const char*)h1s + rbase1 + koff);
          f16x8 a20 = *(const f16x8*)((const char*)h2s + rbase0 + koff);
          f16x8 a21 = *(const f16x8*)((const char*)h2s + rbase1 + koff);
          f16x8 bin8 = *(const f16x8*)(Bin + kt * 512);
          f16x8 bhn8 = *(const f16x8*)(Bhn + kt * 512);
          aI[0] = mfma16(a10, bin8, aI[0]); aI[1] = mfma16(a11, bin8, aI[1]);
          aH[0] = mfma16(a20, bhn8, aH[0]); aH[1] = mfma16(a21, bhn8, aH[1]);
        }
        const int jx = 2 * (jb + colid);
#pragma unroll
        for (int rt = 0; rt < 2; ++rt)
#pragma unroll
          for (int q = 0; q < 16; ++q) {
            const int row = (rt << 5) + (q & 3) + ((q >> 2) << 3) + (khalf << 2);
            float r  = (float)rv[(rt << 1) | (q >> 3)][q & 7];
            float zt = (float)zv[(rt << 1) | (q >> 3)][q & 7];
            float n  = tanh_f(aI[rt][q] + bnic + r * (aH[rt][q] + bnhc));
            float hold = (float)*(const f16*)((const char*)h2s + row * 1024 + (jx ^ ((row & 7) << 4)));
            hv[(c << 2) | (rt << 1) | (q >> 3)][q & 7] = (f16)((1.0f - zt) * n + zt * hold);
          }
      }
    }
    __syncthreads();
#pragma unroll
    for (int c = 0; c < 2; ++c) {
      const int j2 = 2 * (jw + (c << 5) + colid);
#pragma unroll
      for (int rt = 0; rt < 2; ++rt)
#pragma unroll
        for (int q = 0; q < 16; ++q) {
          const int row = (rt << 5) + (q & 3) + ((q >> 2) << 3) + (khalf << 2);
          *(f16*)((char*)h2s + row * 1024 + (j2 ^ ((row & 7) << 4))) = hv[(c << 2) | (rt << 1) | (q >> 3)][q & 7];
        }
    }
    __syncthreads();

    // ================= FC head (all 512 threads) =================
    {
      const int r = lane;
      const int s = wv;
      const char* hb = (const char*)h2s + r * 1024;
      const int pat = (r & 7) << 4;
      float p0 = 0.f, p1 = 0.f, p2 = 0.f;
#pragma unroll
      for (int k8 = 0; k8 < 8; ++k8) {
        const int kt = (s << 3) + k8;
        f16x8 hvv = *(const f16x8*)(hb + ((kt << 4) ^ pat));
#pragma unroll
        for (int i = 0; i < 8; ++i) {
          const float hf = (float)hvv[i];
          const float4 fw4 = *(const float4*)(fcw + ((kt << 3) + i) * 4);
          p0 = fmaf(hf, fw4.x, p0);
          p1 = fmaf(hf, fw4.y, p1);
          p2 = fmaf(hf, fw4.z, p2);
        }
      }
      float* pp = part + ((s << 6) + r) * 4;
      pp[0] = p0; pp[1] = p1; pp[2] = p2;
    }
    __syncthreads();
    if (tid < BT * 3) {
      float acc = fb;
#pragma unroll
      for (int s = 0; s < 8; ++s) acc += part[((s << 6) + rr_) * 4 + oo_];
      float xv = xcar + 0.1f * tanh_f(acc);
      xcar = xv;
      xs16[rr_ * 16 + oo_] = (f16)xv;
      out[(size_t)(b0 + rr_) * 300 + (size_t)t * 3 + oo_] = xv;
    }
    __syncthreads();
  }
}

extern "C" void kernel_launch(void* const* d_in, const int* in_sizes, int n_in,
                              void* d_out, int out_size, void* d_ws, size_t ws_size,
                              hipStream_t stream) {
  const float* z     = (const float*)d_in[0];
  const float* w_ih1 = (const float*)d_in[1];
  const float* w_hh1 = (const float*)d_in[2];
  const float* b_ih1 = (const float*)d_in[3];
  const float* b_hh1 = (const float*)d_in[4];
  const float* w_ih2 = (const float*)d_in[5];
  const float* w_hh2 = (const float*)d_in[6];
  const float* b_ih2 = (const float*)d_in[7];
  const float* b_hh2 = (const float*)d_in[8];
  const float* fc_w  = (const float*)d_in[9];
  const float* fc_b  = (const float*)d_in[10];
  float* out = (float*)d_out;

  f16*   Wp = (f16*)d_ws;                                          // 3 * 1.5 MB packed fp16
  f16*   Wx = (f16*)((char*)d_ws + (size_t)3 * WMAT * 2);          // 48 KB packed w_ih1
  float* Bb = (float*)((char*)d_ws + (size_t)3 * WMAT * 2 + 48 * 512 * 2);

  const int nbatch = in_sizes[0] / 6;

  pack_weights<<<384, 256, 0, stream>>>(w_hh1, Wp);
  pack_weights<<<384, 256, 0, stream>>>(w_ih2, Wp + WMAT);
  pack_weights<<<384, 256, 0, stream>>>(w_hh2, Wp + 2 * WMAT);
  pack_wih1<<<12, 256, 0, stream>>>(w_ih1, Wx);
  pack_bias<<<8, 256, 0, stream>>>(b_ih1, b_hh1, Bb);
  pack_bias<<<8, 256, 0, stream>>>(b_ih2, b_hh2, Bb + 2048);

  gru_fused<<<nbatch / BT, 512, 0, stream>>>(z, fc_w, fc_b, Wp, Wx, Bb, out);
}

// Round 5
// 12645.396 us; speedup vs baseline: 1.9334x; 1.9334x over previous
//
#include <hip/hip_runtime.h>

typedef _Float16 f16;
typedef _Float16 f16x8 __attribute__((ext_vector_type(8)));
typedef float f32x16 __attribute__((ext_vector_type(16)));

#define HID   512
#define BT    32          // batch rows per block
#define NSTEP 100
#define WMAT  786432      // halfs per packed weight matrix (1536*512)

__device__ __forceinline__ float sigmoid_f(float x) {
  return 1.0f / (1.0f + __expf(-x));
}
__device__ __forceinline__ float tanh_f(float x) {
  float e = __expf(2.0f * x);
  return 1.0f - 2.0f / (e + 1.0f);
}
__device__ __forceinline__ f32x16 mfma16(f16x8 a, f16x8 b, f32x16 c) {
  return __builtin_amdgcn_mfma_f32_32x32x16_f16(a, b, c, 0, 0, 0);
}
__device__ __forceinline__ f32x16 zero16() {
  f32x16 z;
#pragma unroll
  for (int i = 0; i < 16; ++i) z[i] = 0.f;
  return z;
}

// ---- weight pack: fp32 [1536][512] row-major -> B-fragment-packed fp16 ----
// layout [ct(48)][kt(32)][lane(64)][i(8)]:
//   gate = ct*32 + (lane&31), k = kt*16 + (lane>>5)*8 + i
__global__ void pack_weights(const float* __restrict__ W, f16* __restrict__ out) {
  int t = blockIdx.x * 256 + threadIdx.x;
  if (t >= 48 * 32 * 64) return;
  int lane = t & 63;
  int kt   = (t >> 6) & 31;
  int ct   = t >> 11;
  int gate = ct * 32 + (lane & 31);
  int k0   = kt * 16 + (lane >> 5) * 8;
  const float* src = W + gate * HID + k0;
  f16x8 v;
#pragma unroll
  for (int i = 0; i < 8; ++i) v[i] = (f16)src[i];
  *(f16x8*)(out + (size_t)t * 8) = v;
}

// w_ih1 [1536][3] -> B-fragments padded to K=16 (zeros for k>=3); 48 tiles x 512 halfs
__global__ void pack_wih1(const float* __restrict__ W, f16* __restrict__ out) {
  int t = blockIdx.x * 256 + threadIdx.x;
  if (t >= 48 * 64) return;
  int lane = t & 63;
  int ct   = t >> 6;
  int gate = ct * 32 + (lane & 31);
  int k0   = (lane >> 5) * 8;
  f16x8 v;
#pragma unroll
  for (int i = 0; i < 8; ++i) {
    int k = k0 + i;
    v[i] = (k < 3) ? (f16)W[gate * 3 + k] : (f16)0;
  }
  *(f16x8*)(out + (size_t)t * 8) = v;
}

// combined biases: [0..1023]=bi+bh (r,z), [1024..1535]=bi_n, [1536..2047]=bh_n
__global__ void pack_bias(const float* __restrict__ bi, const float* __restrict__ bh,
                          float* __restrict__ out) {
  int j = blockIdx.x * 256 + threadIdx.x;
  if (j < 1024)      out[j] = bi[j] + bh[j];
  else if (j < 1536) out[j] = bi[j];
  else if (j < 2048) out[j] = bh[j - 512];
}

// Persistent per-block GRU: block = 32 batch rows, 8 waves, 99 steps.
// h buffers are DOUBLE-BUFFERED (read p, write p^1) so epilogues write h_new
// directly to LDS -> no deferred-write register arrays, no spill.
// h element (row,k) at LDS byte: buf*32768 + row*1024 + ((2k) ^ ((row&7)<<4))
__global__ __launch_bounds__(512, 2) void gru_fused(
    const float* __restrict__ z,
    const float* __restrict__ fc_w,    // [3][512]  fp32
    const float* __restrict__ fc_b,    // [3]
    const f16*  __restrict__ Wp,       // packed Whh1 | Wih2 | Whh2
    const f16*  __restrict__ Wx,       // packed w_ih1 (K=16 padded)
    const float* __restrict__ Bb,      // bias1[2048] | bias2[2048]
    float* __restrict__ out)           // [B][100][3] fp32
{
  __shared__ f16   h1s[2 * BT * HID];   // 64 KB (two 32 KB buffers)
  __shared__ f16   h2s[2 * BT * HID];   // 64 KB
  __shared__ f16   xs16[BT * 16];       // 1 KB  (x as MFMA A-tile, K=16 zero-padded)
  __shared__ float fcwT[3 * HID];       // 6 KB  (fc_w transposed [(k%32)*16 + k/32])
  __shared__ float xsf[BT * 4];         // 0.5 KB (fp32 x state)

  const int tid  = threadIdx.x;
  const int lane = tid & 63;
  const int wv   = tid >> 6;
  const int b0   = blockIdx.x * BT;

  {
    f16x8 z8 = {0, 0, 0, 0, 0, 0, 0, 0};
    for (int i = tid; i < BT * HID / 8; i += 512) {
      ((f16x8*)h1s)[i] = z8;              // zero buffer 0 only
      ((f16x8*)h2s)[i] = z8;
    }
    if (tid < BT * 2) ((f16x8*)xs16)[tid] = z8;
    if (tid < HID) {
      const int pos = ((tid & 31) << 4) + (tid >> 5);
      fcwT[pos]              = fc_w[tid];
      fcwT[512 + pos]        = fc_w[512 + tid];
      fcwT[1024 + pos]       = fc_w[1024 + tid];
    }
  }
  __syncthreads();
  if (tid < BT * 3) {
    const int rr = tid / 3, oo = tid - rr * 3;
    float v = z[(size_t)(b0 + rr) * 6 + 3 + oo];
    xsf[rr * 4 + oo] = v;
    xs16[rr * 16 + oo] = (f16)v;
    out[(size_t)(b0 + rr) * 300 + oo] = v;     // t = 0 output
  }
  __syncthreads();

  const int colid = lane & 31;
  const int khalf = lane >> 5;
  const int klo   = khalf << 4;
  const int patA  = (colid & 7) << 4;
  const int rbase = colid * 1024;
  const int jw    = wv << 6;

  const f16* W1  = Wp;
  const f16* Wi2 = Wp + WMAT;
  const f16* Wh2 = Wp + 2 * WMAT;

  // bias registers (constant over t)
  const int j0 = jw + colid, j1 = jw + 32 + colid;
  const float b1r0 = Bb[j0],         b1r1 = Bb[j1];
  const float b1z0 = Bb[512 + j0],   b1z1 = Bb[512 + j1];
  const float b1ni0 = Bb[1024 + j0], b1ni1 = Bb[1024 + j1];
  const float b1nh0 = Bb[1536 + j0], b1nh1 = Bb[1536 + j1];
  const float b2r0 = Bb[2048 + j0],         b2r1 = Bb[2048 + j1];
  const float b2z0 = Bb[2048 + 512 + j0],   b2z1 = Bb[2048 + 512 + j1];
  const float b2ni0 = Bb[2048 + 1024 + j0], b2ni1 = Bb[2048 + 1024 + j1];
  const float b2nh0 = Bb[2048 + 1536 + j0], b2nh1 = Bb[2048 + 1536 + j1];

  const float fb0 = fc_b[0], fb1 = fc_b[1], fb2 = fc_b[2];
  const int xoff = colid * 32 + klo;

  int p = 0;
  for (int t = 1; t < NSTEP; ++t) {
    const int q = p ^ 1;
    const char* h1r = (const char*)h1s + (p << 15);
    char*       h1w = (char*)h1s + (q << 15);
    const char* h2r = (const char*)h2s + (p << 15);
    char*       h2w = (char*)h2s + (q << 15);

    // ================= GRU layer 1: reads h1r + xs16, writes h1w =================
#pragma unroll
    for (int c = 0; c < 2; ++c) {
      const int jb = jw + (c << 5);
      const int ct = jb >> 5;                 // 0..15
      f32x16 aR, aZ, aN, aNx;
      {
        f16x8 ax  = *(const f16x8*)((const char*)xs16 + xoff);
        f16x8 brx = *(const f16x8*)(Wx + (size_t)ct * 512 + lane * 8);
        f16x8 bzx = *(const f16x8*)(Wx + (size_t)(16 + ct) * 512 + lane * 8);
        f16x8 bnx = *(const f16x8*)(Wx + (size_t)(32 + ct) * 512 + lane * 8);
        f32x16 zz = zero16();
        aR  = mfma16(ax, brx, zz);
        aZ  = mfma16(ax, bzx, zz);
        aNx = mfma16(ax, bnx, zz);
        aN  = zz;
      }
      const f16* Br = W1 + (size_t)ct * 16384 + lane * 8;
      const f16* Bz = W1 + (size_t)(16 + ct) * 16384 + lane * 8;
      const f16* Bn = W1 + (size_t)(32 + ct) * 16384 + lane * 8;
#pragma unroll 2
      for (int kt = 0; kt < 32; ++kt) {
        const int koff = ((kt << 5) | klo) ^ patA;
        f16x8 a0 = *(const f16x8*)(h1r + rbase + koff);
        aR = mfma16(a0, *(const f16x8*)(Br + kt * 512), aR);
        aZ = mfma16(a0, *(const f16x8*)(Bz + kt * 512), aZ);
        aN = mfma16(a0, *(const f16x8*)(Bn + kt * 512), aN);
      }
      const float brc  = c ? b1r1 : b1r0;
      const float bzc  = c ? b1z1 : b1z0;
      const float bnic = c ? b1ni1 : b1ni0;
      const float bnhc = c ? b1nh1 : b1nh0;
      const int jx = 2 * (jb + colid);
#pragma unroll
      for (int qq = 0; qq < 16; ++qq) {
        const int row = (qq & 3) + ((qq >> 2) << 3) + (khalf << 2);
        const int off = row * 1024 + (jx ^ ((row & 7) << 4));
        float r  = sigmoid_f(aR[qq] + brc);
        float zt = sigmoid_f(aZ[qq] + bzc);
        float n  = tanh_f(aNx[qq] + bnic + r * (aN[qq] + bnhc));
        float hold = (float)*(const f16*)(h1r + off);
        *(f16*)(h1w + off) = (f16)((1.0f - zt) * n + zt * hold);
      }
    }
    __syncthreads();

    // ================= GRU layer 2: reads h1w (new) + h2r, writes h2w =================
#pragma unroll
    for (int c = 0; c < 2; ++c) {
      const int jb = jw + (c << 5);
      const int ct = jb >> 5;
      f32x16 aR = zero16(), aZ = zero16(), aI = zero16(), aH = zero16();
      const f16* Bir = Wi2 + (size_t)ct * 16384 + lane * 8;
      const f16* Biz = Wi2 + (size_t)(16 + ct) * 16384 + lane * 8;
      const f16* Bin = Wi2 + (size_t)(32 + ct) * 16384 + lane * 8;
      const f16* Bhr = Wh2 + (size_t)ct * 16384 + lane * 8;
      const f16* Bhz = Wh2 + (size_t)(16 + ct) * 16384 + lane * 8;
      const f16* Bhn = Wh2 + (size_t)(32 + ct) * 16384 + lane * 8;
#pragma unroll 2
      for (int kt = 0; kt < 32; ++kt) {
        const int koff = ((kt << 5) | klo) ^ patA;
        f16x8 a1 = *(const f16x8*)(h1w + rbase + koff);
        f16x8 a2 = *(const f16x8*)(h2r + rbase + koff);
        aR = mfma16(a1, *(const f16x8*)(Bir + kt * 512), aR);
        aR = mfma16(a2, *(const f16x8*)(Bhr + kt * 512), aR);
        aZ = mfma16(a1, *(const f16x8*)(Biz + kt * 512), aZ);
        aZ = mfma16(a2, *(const f16x8*)(Bhz + kt * 512), aZ);
        aI = mfma16(a1, *(const f16x8*)(Bin + kt * 512), aI);
        aH = mfma16(a2, *(const f16x8*)(Bhn + kt * 512), aH);
      }
      const float brc  = c ? b2r1 : b2r0;
      const float bzc  = c ? b2z1 : b2z0;
      const float bnic = c ? b2ni1 : b2ni0;
      const float bnhc = c ? b2nh1 : b2nh0;
      const int jx = 2 * (jb + colid);
#pragma unroll
      for (int qq = 0; qq < 16; ++qq) {
        const int row = (qq & 3) + ((qq >> 2) << 3) + (khalf << 2);
        const int off = row * 1024 + (jx ^ ((row & 7) << 4));
        float r  = sigmoid_f(aR[qq] + brc);
        float zt = sigmoid_f(aZ[qq] + bzc);
        float n  = tanh_f(aI[qq] + bnic + r * (aH[qq] + bnhc));
        float hold = (float)*(const f16*)(h2r + off);
        *(f16*)(h2w + off) = (f16)((1.0f - zt) * n + zt * hold);
      }
    }
    __syncthreads();

    // ================= FC head: wave-local shuffle reduction =================
    {
      const int row = (wv << 2) + (lane >> 4);   // each wave: 4 rows
      const int sl  = lane & 15;                 // 16 k-slices of 32
      const char* hb = h2w + row * 1024;
      const int pat = (row & 7) << 4;
      float p0 = 0.f, p1 = 0.f, p2 = 0.f;
#pragma unroll
      for (int j = 0; j < 4; ++j) {
        f16x8 hv8 = *(const f16x8*)(hb + ((((sl << 2) + j) << 4) ^ pat));
#pragma unroll
        for (int i = 0; i < 8; ++i) {
          const float hf = (float)hv8[i];
          const int kk = (j << 3) + i;           // k % 32
          p0 = fmaf(hf, fcwT[(kk << 4) + sl], p0);
          p1 = fmaf(hf, fcwT[512 + (kk << 4) + sl], p1);
          p2 = fmaf(hf, fcwT[1024 + (kk << 4) + sl], p2);
        }
      }
#pragma unroll
      for (int m = 1; m < 16; m <<= 1) {
        p0 += __shfl_xor(p0, m, 64);
        p1 += __shfl_xor(p1, m, 64);
        p2 += __shfl_xor(p2, m, 64);
      }
      if (sl == 0) {
        float x0 = xsf[(row << 2) + 0] + 0.1f * tanh_f(p0 + fb0);
        float x1 = xsf[(row << 2) + 1] + 0.1f * tanh_f(p1 + fb1);
        float x2 = xsf[(row << 2) + 2] + 0.1f * tanh_f(p2 + fb2);
        xsf[(row << 2) + 0] = x0;  xs16[row * 16 + 0] = (f16)x0;
        xsf[(row << 2) + 1] = x1;  xs16[row * 16 + 1] = (f16)x1;
        xsf[(row << 2) + 2] = x2;  xs16[row * 16 + 2] = (f16)x2;
        float* op = out + (size_t)(b0 + row) * 300 + (size_t)t * 3;
        op[0] = x0; op[1] = x1; op[2] = x2;
      }
    }
    __syncthreads();
    p ^= 1;
  }
}

extern "C" void kernel_launch(void* const* d_in, const int* in_sizes, int n_in,
                              void* d_out, int out_size, void* d_ws, size_t ws_size,
                              hipStream_t stream) {
  const float* z     = (const float*)d_in[0];
  const float* w_ih1 = (const float*)d_in[1];
  const float* w_hh1 = (const float*)d_in[2];
  const float* b_ih1 = (const float*)d_in[3];
  const float* b_hh1 = (const float*)d_in[4];
  const float* w_ih2 = (const float*)d_in[5];
  const float* w_hh2 = (const float*)d_in[6];
  const float* b_ih2 = (const float*)d_in[7];
  const float* b_hh2 = (const float*)d_in[8];
  const float* fc_w  = (const float*)d_in[9];
  const float* fc_b  = (const float*)d_in[10];
  float* out = (float*)d_out;

  f16*   Wp = (f16*)d_ws;                                          // 3 * 1.5 MB packed fp16
  f16*   Wx = (f16*)((char*)d_ws + (size_t)3 * WMAT * 2);          // 48 KB packed w_ih1
  float* Bb = (float*)((char*)d_ws + (size_t)3 * WMAT * 2 + 48 * 512 * 2);

  const int nbatch = in_sizes[0] / 6;

  pack_weights<<<384, 256, 0, stream>>>(w_hh1, Wp);
  pack_weights<<<384, 256, 0, stream>>>(w_ih2, Wp + WMAT);
  pack_weights<<<384, 256, 0, stream>>>(w_hh2, Wp + 2 * WMAT);
  pack_wih1<<<12, 256, 0, stream>>>(w_ih1, Wx);
  pack_bias<<<8, 256, 0, stream>>>(b_ih1, b_hh1, Bb);
  pack_bias<<<8, 256, 0, stream>>>(b_ih2, b_hh2, Bb + 2048);

  gru_fused<<<nbatch / BT, 512, 0, stream>>>(z, fc_w, fc_b, Wp, Wx, Bb, out);
}